// Round 9
// baseline (2100.082 us; speedup 1.0000x reference)
//
#include <hip/hip_runtime.h>
#include <cstddef>

// ---------------------------------------------------------------------------
// SNN forward, feed-forward pipeline. CORRECTNESS CONTRACT (R2 post-mortem):
// the v>0.33 Heaviside amplifies ANY accumulation-order change into spike
// flips vs the numpy reference (R2's exact-integer MFMA failed at 2.4e-2
// despite being MORE accurate). All arithmetic chains are verbatim R3
// (passed, absmax 1.5e-5): per (t,b,o), sequential-in-ascending-j fp32 fmaf
// with av in {0,scale}; encoder/LIF/LI loops unchanged.
//
// R4: runtime-indexed acc -> scratch spill. R5: register prefetch -> spill.
// R6 (WIN 2045us): async global_load_lds double-buffer, VALUBusy 82%.
// R7: bounds(256,3) -> acc spill (VGPR 84, FETCH 659MB). IRON LAW: 128 acc
// regs stay resident; 2 waves/SIMD is the operating point.
// R8: f4v operands — neutral (SROA had already cleaned R6's inner loop).
// R9: BK=64 — two 32KB buffers, barriers halved (64->32 for L1), stage/mask
// overhead amortized over 8192 FMAs. Masks loaded post-barrier (not
// prefetched) so register count stays AT R8 level (16 mask words either way).
// j-order h-major-then-j == ascending global j -> bit-identical.
// ---------------------------------------------------------------------------

#define THREADS 256

typedef float f4v __attribute__((ext_vector_type(4)));

#if __has_builtin(__builtin_amdgcn_sbfe)
#define BIT_SPLAT(m, j) __builtin_amdgcn_sbfe((int)(m), (unsigned)(j), 1u)
#else
#define BIT_SPLAT(m, j) (((int)((m) << (31 - (j)))) >> 31)
#endif

__device__ __forceinline__ void gl_lds16(const float* g, float* l) {
#if __has_builtin(__builtin_amdgcn_global_load_lds)
  __builtin_amdgcn_global_load_lds(
      (const __attribute__((address_space(1))) void*)g,
      (__attribute__((address_space(3))) void*)l, 16, 0, 0);
#else
  *(float4*)l = *(const float4*)g;   // sync fallback (correct, slower)
#endif
}

// WT offsets (floats): WT1[2048][512], WT2[512][512], WT3[512][256],
// WT4[256][128] (w4 zero-padded 100->128 cols)
#define WOFF1 0
#define WOFF2 1048576
#define WOFF3 1310720
#define WOFF4 1441792
#define WTOT  1474560

__global__ __launch_bounds__(THREADS) void prep_kernel(
    const float* __restrict__ w1, const float* __restrict__ w2,
    const float* __restrict__ w3, const float* __restrict__ w4,
    float* __restrict__ wt)
{
  int idx = blockIdx.x * THREADS + threadIdx.x;
  if (idx >= WTOT) return;
  if (idx < WOFF2) {
    int j = idx >> 9, o = idx & 511;
    wt[idx] = w1[o * 2048 + j];
  } else if (idx < WOFF3) {
    int r = idx - WOFF2, j = r >> 9, o = r & 511;
    wt[idx] = w2[o * 512 + j];
  } else if (idx < WOFF4) {
    int r = idx - WOFF3, j = r >> 8, o = r & 255;
    wt[idx] = w3[o * 512 + j];
  } else {
    int r = idx - WOFF4, j = r >> 7, o = r & 127;
    wt[idx] = (o < 100) ? w4[o * 256 + j] : 0.0f;
  }
}

// Encoder (verbatim R3 arithmetic) fused with 32x32 bit-transpose:
// writes emT word(b, c, t) = bits over jj (j = c*32+jj).
__global__ __launch_bounds__(THREADS) void enc_kernel(
    const float* __restrict__ x, const float* __restrict__ fscale,
    unsigned* __restrict__ emT, int b0)
{
  __shared__ unsigned sm[8][33];
  int tile = threadIdx.x >> 5, l = threadIdx.x & 31;
  size_t gt = (size_t)blockIdx.x * 8 + tile;     // gt = b*64 + c
  int c = (int)(gt & 63);
  size_t b = gt >> 6;
  float cc = 2.0f * fscale[0] * x[((size_t)(b0 + b) << 11) + c * 32 + l];
  float v = 0.0f;
  unsigned m = 0u;
#pragma unroll
  for (int t = 0; t < 32; ++t) {
    v = v + 0.1f * (cc - v);
    unsigned z = ((v - 0.33f) > 0.0f) ? 1u : 0u;
    m |= z << t;
    if (z) v = 0.0f;
  }
  sm[tile][l] = m;
  __syncthreads();
  unsigned w = 0;
#pragma unroll
  for (int jj = 0; jj < 32; ++jj) w |= ((sm[tile][jj] >> l) & 1u) << jj;
  emT[(gt << 5) + l] = w;
}

// ---------------------------------------------------------------------------
// Fused GEMM(+LIF / +LI readout), async double-buffered W staging, BK=64.
//   mT:  bit-transposed input masks, word (b, c, t) = bits over jj (c: 32-j)
//   WT:  [j][o] pre-transposed weights
// Block: OTILE o x BB b x all 32 t. Thread: t = tid&31, og = tid>>5,
// acc[BB][OTILE/8] (static indices only!). Epilogue per bb: acc -> LDS (t,o)
// tile -> verbatim LIF per o -> 32x32 bit-transpose -> mTout (or LI -> out).
// ---------------------------------------------------------------------------
template <int OTILE, int BB, bool FINAL>
__global__ __launch_bounds__(THREADS, 2) void gemm_fused(
    const unsigned* __restrict__ mT, const float* __restrict__ WT,
    int J, int O, const float* __restrict__ es,
    unsigned* __restrict__ mTout, int ncO,
    float* __restrict__ out, int bbase)
{
  constexpr int OVEC = OTILE / 8;
  constexpr int RS = OTILE + 1;              // padded epilogue row stride
  constexpr int CH = 64 * OTILE;             // floats per BK=64 buffer (32 KB)
  __shared__ float lds[2 * CH];              // 64 KB total
  static_assert(32 * RS <= 2 * CH, "epilogue overlay fits");
  const int tid = threadIdx.x;
  const int t = tid & 31, og = tid >> 5;
  const int lane = tid & 63, wv = tid >> 6;
  const int o0 = blockIdx.x * OTILE;
  const int btile = blockIdx.y * BB;
  const int nc = J >> 5;                     // 32-j chunks (mask indexing)
  const int nb = J >> 6;                     // 64-j blocks
  const float scale = es ? 5.0f * es[0] : 1.0f;   // same expr as R3
  const int scale_i = __float_as_int(scale);
  float* const buf0 = lds;
  float* const buf1 = lds + CH;

  float acc[BB][OVEC];
#pragma unroll
  for (int bb = 0; bb < BB; ++bb)
#pragma unroll
    for (int oo = 0; oo < OVEC; ++oo) acc[bb][oo] = 0.0f;

  // async-stage one 64 x OTILE W block: 64 lanes x 16 B per instruction,
  // LDS dest = uniform base + lane*16 (contiguous row-major), no VGPR staging
  auto stage = [&](int cb, float* buf) {
    constexpr int IPW = CH / 256 / 4;        // instructions per wave-slot
#pragma unroll
    for (int i = 0; i < IPW; ++i) {
      int inst = wv * IPW + i;
      int flat = inst * 256 + lane * 4;
      int j = flat / OTILE, col = flat % OTILE;
      gl_lds16(WT + (size_t)(cb * 64 + j) * O + o0 + col, buf + flat);
    }
  };
  // masks for a 64-j block: 2 words per bb, loaded AFTER the barrier
  // (latency amortized over 8192 FMAs, covered by co-resident wave;
  // keeps register count at R8 level — no mn double-buffer)
  auto fma_block = [&](int cb, const float* buf) {
    unsigned m[BB][2];
#pragma unroll
    for (int bb = 0; bb < BB; ++bb)
#pragma unroll
      for (int h = 0; h < 2; ++h)
        m[bb][h] = mT[(((size_t)(btile + bb) * nc + cb * 2 + h) << 5) + t];
#pragma unroll
    for (int h = 0; h < 2; ++h) {            // global j = cb*64+h*32+j: asc.
#pragma unroll 8
      for (int j = 0; j < 32; ++j) {
        float av[BB];
#pragma unroll
        for (int bb = 0; bb < BB; ++bb)  // av = bit ? scale : 0 (bit-identical)
          av[bb] = __int_as_float(BIT_SPLAT(m[bb][h], j) & scale_i);
        const f4v* wrow = (const f4v*)(buf + (h * 32 + j) * OTILE + og * OVEC);
#pragma unroll
        for (int q = 0; q < OVEC / 4; ++q) {
          const f4v w = wrow[q];
#pragma unroll
          for (int bb = 0; bb < BB; ++bb)
#pragma unroll
            for (int oo = 0; oo < 4; ++oo)
              acc[bb][q * 4 + oo] = fmaf(av[bb], w[oo], acc[bb][q * 4 + oo]);
        }
      }
    }
  };

  stage(0, buf0);

  for (int cb = 0; cb < nb; cb += 2) {       // nb even (32/8/8/4)
    __syncthreads();                         // buf0 loads drained; buf1 free
    if (cb + 1 < nb) stage(cb + 1, buf1);
    fma_block(cb, buf0);
    __syncthreads();                         // buf1 loads drained; buf0 free
    if (cb + 2 < nb) stage(cb + 2, buf0);
    fma_block(cb + 1, buf1);
  }

  // ---- epilogue: per bb, (t,o) transpose + verbatim LIF / LI ----
  // FULLY unrolled: acc indices must stay static (R4 spill post-mortem).
  float* const sbuf = lds;
#pragma unroll
  for (int bb = 0; bb < BB; ++bb) {
    __syncthreads();
#pragma unroll
    for (int k = 0; k < OVEC; ++k)
      sbuf[t * RS + og * OVEC + k] = acc[bb][k];
    __syncthreads();
    if (FINAL) {
      if (tid < OTILE) {
        float v = 0.0f, cur = 0.0f;
#pragma unroll
        for (int t2 = 0; t2 < 32; ++t2) {          // verbatim R3 out_li
          v = v + 0.1f * (cur - v);
          cur = 0.8f * cur + sbuf[t2 * RS + tid];
        }
        if (tid < 100)
          out[(size_t)(bbase + btile + bb) * 100 + tid] = v;
      }
    } else {
      unsigned w = 0;
      if (tid < OTILE) {
        float v = 0.0f, cur = 0.0f;
#pragma unroll
        for (int t2 = 0; t2 < 32; ++t2) {          // verbatim R3 lif_int
          v = v + 0.1f * (cur - v);
          unsigned z = ((v - 0.33f) > 0.0f) ? 1u : 0u;
          w |= z << t2;
          if (z) v = 0.0f;
          cur = 0.8f * cur + sbuf[t2 * RS + tid];
        }
      }
      __syncthreads();
      if (tid < OTILE) ((unsigned*)sbuf)[tid] = w;
      __syncthreads();
      if (tid < OTILE) {
        int cg = tid >> 5, tl = tid & 31;
        unsigned W2 = 0;
#pragma unroll
        for (int jj = 0; jj < 32; ++jj)
          W2 |= ((((unsigned*)sbuf)[cg * 32 + jj] >> tl) & 1u) << jj;
        mTout[((size_t)(btile + bb) * ncO + (o0 >> 5) + cg) * 32 + tl] = W2;
      }
    }
  }
}

extern "C" void kernel_launch(void* const* d_in, const int* in_sizes, int n_in,
                              void* d_out, int out_size, void* d_ws, size_t ws_size,
                              hipStream_t stream)
{
  const float* x  = (const float*)d_in[0];
  const float* w1 = (const float*)d_in[1];
  const float* w2 = (const float*)d_in[2];
  const float* w3 = (const float*)d_in[3];
  const float* w4 = (const float*)d_in[4];
  const float* fs = (const float*)d_in[5];
  const float* es = (const float*)d_in[6];
  float* out = (float*)d_out;
  (void)in_sizes; (void)n_in; (void)out_size;

  // ws: WT (5.9 MB) + emT + s1mT + s2mT + s3mT
  int Bc = 2048;
  auto need = [](int bc) -> size_t {
    return ((size_t)WTOT + (size_t)bc * (2048 + 512 + 512 + 256)) * 4;
  };
  while (Bc > 64 && need(Bc) > ws_size) Bc >>= 1;

  float* WT = (float*)d_ws;
  unsigned* emT  = (unsigned*)(WT + WTOT);
  unsigned* s1mT = emT  + (size_t)Bc * 2048;
  unsigned* s2mT = s1mT + (size_t)Bc * 512;
  unsigned* s3mT = s2mT + (size_t)Bc * 512;

  prep_kernel<<<(WTOT + THREADS - 1) / THREADS, THREADS, 0, stream>>>(
      w1, w2, w3, w4, WT);

  for (int b0 = 0; b0 < 2048; b0 += Bc) {
    enc_kernel<<<Bc * 8, THREADS, 0, stream>>>(x, fs, emT, b0);
    // L1: J=2048 -> O=512, scale = 5*encoder_scalar
    gemm_fused<128, 8, false><<<dim3(4, Bc / 8), THREADS, 0, stream>>>(
        emT, WT + WOFF1, 2048, 512, es, s1mT, 16, nullptr, 0);
    // L2: J=512 -> O=512
    gemm_fused<128, 8, false><<<dim3(4, Bc / 8), THREADS, 0, stream>>>(
        s1mT, WT + WOFF2, 512, 512, nullptr, s2mT, 16, nullptr, 0);
    // L3: J=512 -> O=256
    gemm_fused<128, 8, false><<<dim3(2, Bc / 8), THREADS, 0, stream>>>(
        s2mT, WT + WOFF3, 512, 256, nullptr, s3mT, 8, nullptr, 0);
    // L4 (readout): J=256 -> O=128 (padded), LI epilogue -> out
    gemm_fused<128, 8, true><<<dim3(1, Bc / 8), THREADS, 0, stream>>>(
        s3mT, WT + WOFF4, 256, 128, nullptr, nullptr, 0, out, b0);
  }
}

// Round 10
// 1190.503 us; speedup vs baseline: 1.7640x; 1.7640x over previous
//
#include <hip/hip_runtime.h>
#include <cstddef>

// ---------------------------------------------------------------------------
// SNN forward, feed-forward pipeline. CORRECTNESS CONTRACT: reproduce R3's
// sequential-in-ascending-j fp32 fmaf chain per (t,b,o) (passed, 1.5e-5).
// KEY FACT (R10): fmaf(+0, w, acc) == acc EXACTLY (acc never -0: starts +0,
// x+(-x) rounds to +0), so SKIPPING zero-spike j's is bit-identical.
//
// Layout: wave = (b, 256-o slice); lane = 4 o's; t in registers
// (acc[32][NAO]). Masks in em[b][j] format (bits over t, wave-uniform word):
//   - j with word==0 skipped via SCALAR branch (wave-uniform)
//   - active j: 1 ds_read_b128 of W[j] per lane, reused over 32 t
//   - per-t gate on the SCALAR pipe (av = SGPR operand to v_fmac)
//   - LIF epilogue integrates over t in registers: NO transposes anywhere
// W staging: R6's async global_load_lds double-buffer (32 KB chunks).
// R4/R5/R7 lesson: acc arrays static-indexed, no reg prefetch, bounds(256,2).
// ---------------------------------------------------------------------------

#define THREADS 256

typedef float f4v __attribute__((ext_vector_type(4)));
typedef float f2v __attribute__((ext_vector_type(2)));

__device__ __forceinline__ void gl_lds16(const float* g, float* l) {
#if __has_builtin(__builtin_amdgcn_global_load_lds)
  __builtin_amdgcn_global_load_lds(
      (const __attribute__((address_space(1))) void*)g,
      (__attribute__((address_space(3))) void*)l, 16, 0, 0);
#else
  *(float4*)l = *(const float4*)g;   // sync fallback (correct, slower)
#endif
}

// WT offsets (floats): WT1[2048][512], WT2[512][512], WT3[512][256],
// WT4[256][128] (w4 zero-padded 100->128 cols)
#define WOFF1 0
#define WOFF2 1048576
#define WOFF3 1310720
#define WOFF4 1441792
#define WTOT  1474560

__global__ __launch_bounds__(THREADS) void prep_kernel(
    const float* __restrict__ w1, const float* __restrict__ w2,
    const float* __restrict__ w3, const float* __restrict__ w4,
    float* __restrict__ wt)
{
  int idx = blockIdx.x * THREADS + threadIdx.x;
  if (idx >= WTOT) return;
  if (idx < WOFF2) {
    int j = idx >> 9, o = idx & 511;
    wt[idx] = w1[o * 2048 + j];
  } else if (idx < WOFF3) {
    int r = idx - WOFF2, j = r >> 9, o = r & 511;
    wt[idx] = w2[o * 512 + j];
  } else if (idx < WOFF4) {
    int r = idx - WOFF3, j = r >> 8, o = r & 255;
    wt[idx] = w3[o * 512 + j];
  } else {
    int r = idx - WOFF4, j = r >> 7, o = r & 127;
    wt[idx] = (o < 100) ? w4[o * 256 + j] : 0.0f;
  }
}

// Encoder (verbatim R1/R3 arithmetic); writes em[b][j] word = bits over t.
__global__ __launch_bounds__(THREADS) void enc_kernel(
    const float* __restrict__ x, const float* __restrict__ fscale,
    unsigned* __restrict__ em, int b0)
{
  int idx = blockIdx.x * THREADS + threadIdx.x;
  int b = idx >> 11, j = idx & 2047;
  float c = 2.0f * fscale[0] * x[((size_t)(b0 + b) << 11) + j];
  float v = 0.0f;
  unsigned m = 0u;
#pragma unroll
  for (int t = 0; t < 32; ++t) {
    v = v + 0.1f * (c - v);
    unsigned z = ((v - 0.33f) > 0.0f) ? 1u : 0u;
    m |= z << t;
    if (z) v = 0.0f;
  }
  em[idx] = m;
}

// ---------------------------------------------------------------------------
// Sparse-j fused GEMM(+LIF / +LI readout).
//   mIn: em-format masks [b][J], word = bits over t (wave-uniform per j)
//   WT:  [j][o] pre-transposed weights
// Block: 4 waves; wave = (b, oh o-slice); lane owns NAO consecutive o's,
// acc[32][NAO] holds all t. j skipped when word==0 (bit-exact identity).
// ---------------------------------------------------------------------------
template <int O, bool FINAL>
__global__ __launch_bounds__(THREADS, 2) void gemm_sparse(
    const unsigned* __restrict__ mIn, const float* __restrict__ WT,
    int J, const float* __restrict__ es,
    unsigned* __restrict__ mOut, float* __restrict__ out, int bbase)
{
  constexpr int NAO = (O >= 256) ? 4 : 2;    // o's per lane
  constexpr int WPB = O / (64 * NAO);        // waves per b (1 or 2)
  constexpr int BPB = 4 / WPB;               // b's per block
  constexpr int BK  = 8192 / O;              // j rows per 32KB chunk
  constexpr int CH  = 8192;                  // floats per buffer
  static_assert(BK % 4 == 0, "uint4 mask loads");
  __shared__ float lds[2 * CH];              // 64 KB double buffer
  const int tid = threadIdx.x;
  const int lane = tid & 63, wvid = tid >> 6;
  const int b = blockIdx.x * BPB + wvid / WPB;
  const int obase = (wvid % WPB) * (64 * NAO) + lane * NAO;
  const int nb = J / BK;
  float scalef = es ? 5.0f * es[0] : 1.0f;   // same expr as R3
  const int scale_i =
      __builtin_amdgcn_readfirstlane(__float_as_int(scalef));
  float* const buf0 = lds;
  float* const buf1 = lds + CH;

  float acc[32][NAO];
#pragma unroll
  for (int t = 0; t < 32; ++t)
#pragma unroll
    for (int k = 0; k < NAO; ++k) acc[t][k] = 0.0f;

  const unsigned* mrow = mIn + (size_t)b * J;

  // async-stage one BK x O chunk (flat 32 KB): lane*16B dest pattern
  auto stage = [&](int cb, float* buf) {
#pragma unroll
    for (int i = 0; i < CH / THREADS / 4; ++i) {
      int flat = (tid + i * THREADS) * 4;
      gl_lds16(WT + (size_t)cb * CH + flat, buf + flat);
    }
  };

  auto fma_chunk = [&](int cb, const float* buf) {
    uint4 mw[BK / 4];
#pragma unroll
    for (int q = 0; q < BK / 4; ++q)
      mw[q] = ((const uint4*)(mrow + cb * BK))[q];   // uniform address
    unsigned mwa[BK];
#pragma unroll
    for (int q = 0; q < BK / 4; ++q) {
      mwa[4 * q + 0] = mw[q].x; mwa[4 * q + 1] = mw[q].y;
      mwa[4 * q + 2] = mw[q].z; mwa[4 * q + 3] = mw[q].w;
    }
#pragma unroll
    for (int j = 0; j < BK; ++j) {
      const unsigned w =
          (unsigned)__builtin_amdgcn_readfirstlane((int)mwa[j]);
      if (w) {                                 // wave-uniform scalar skip
        if constexpr (NAO == 4) {
          const f4v wv = *(const f4v*)(buf + j * O + obase);
#pragma unroll
          for (int t = 0; t < 32; ++t) {
            // av = bit(w,t) ? scale : 0 — scalar-pipe ops, SGPR operand
            float av = __int_as_float(
                (int)((((int)(w << (31 - t))) >> 31) & scale_i));
#pragma unroll
            for (int k = 0; k < 4; ++k)
              acc[t][k] = fmaf(av, wv[k], acc[t][k]);
          }
        } else {
          const f2v wv = *(const f2v*)(buf + j * O + obase);
#pragma unroll
          for (int t = 0; t < 32; ++t) {
            float av = __int_as_float(
                (int)((((int)(w << (31 - t))) >> 31) & scale_i));
#pragma unroll
            for (int k = 0; k < 2; ++k)
              acc[t][k] = fmaf(av, wv[k], acc[t][k]);
          }
        }
      }
    }
  };

  stage(0, buf0);
  for (int cb = 0; cb < nb; cb += 2) {       // nb even (128/32/16/4)
    __syncthreads();                         // buf0 drained; buf1 free
    if (cb + 1 < nb) stage(cb + 1, buf1);
    fma_chunk(cb, buf0);
    __syncthreads();                         // buf1 drained; buf0 free
    if (cb + 2 < nb) stage(cb + 2, buf0);
    fma_chunk(cb + 1, buf1);
  }

  // ---- epilogue: all in registers (t lives in the lane), no barriers ----
#pragma unroll
  for (int k = 0; k < NAO; ++k) {
    if (FINAL) {
      float v = 0.0f, cur = 0.0f;
#pragma unroll
      for (int t2 = 0; t2 < 32; ++t2) {      // verbatim R3 out_li
        v = v + 0.1f * (cur - v);
        cur = 0.8f * cur + acc[t2][k];
      }
      int o = obase + k;
      if (o < 100) out[(size_t)(bbase + b) * 100 + o] = v;
    } else {
      float v = 0.0f, cur = 0.0f;
      unsigned zw = 0u;
#pragma unroll
      for (int t2 = 0; t2 < 32; ++t2) {      // verbatim R3 lif_int
        v = v + 0.1f * (cur - v);
        unsigned z = ((v - 0.33f) > 0.0f) ? 1u : 0u;
        zw |= z << t2;
        if (z) v = 0.0f;
        cur = 0.8f * cur + acc[t2][k];
      }
      mOut[(size_t)b * O + obase + k] = zw;  // em-format for next layer
    }
  }
}

extern "C" void kernel_launch(void* const* d_in, const int* in_sizes, int n_in,
                              void* d_out, int out_size, void* d_ws, size_t ws_size,
                              hipStream_t stream)
{
  const float* x  = (const float*)d_in[0];
  const float* w1 = (const float*)d_in[1];
  const float* w2 = (const float*)d_in[2];
  const float* w3 = (const float*)d_in[3];
  const float* w4 = (const float*)d_in[4];
  const float* fs = (const float*)d_in[5];
  const float* es = (const float*)d_in[6];
  float* out = (float*)d_out;
  (void)in_sizes; (void)n_in; (void)out_size;

  // ws: WT (5.9 MB) + em + s1m + s2m + s3m (all em-format words)
  int Bc = 2048;
  auto need = [](int bc) -> size_t {
    return ((size_t)WTOT + (size_t)bc * (2048 + 512 + 512 + 256)) * 4;
  };
  while (Bc > 64 && need(Bc) > ws_size) Bc >>= 1;

  float* WT = (float*)d_ws;
  unsigned* em  = (unsigned*)(WT + WTOT);
  unsigned* s1m = em  + (size_t)Bc * 2048;
  unsigned* s2m = s1m + (size_t)Bc * 512;
  unsigned* s3m = s2m + (size_t)Bc * 512;

  prep_kernel<<<(WTOT + THREADS - 1) / THREADS, THREADS, 0, stream>>>(
      w1, w2, w3, w4, WT);

  for (int b0 = 0; b0 < 2048; b0 += Bc) {
    enc_kernel<<<(Bc * 2048) / THREADS, THREADS, 0, stream>>>(x, fs, em, b0);
    // L1: J=2048 -> O=512, scale = 5*encoder_scalar
    gemm_sparse<512, false><<<Bc / 2, THREADS, 0, stream>>>(
        em, WT + WOFF1, 2048, es, s1m, nullptr, 0);
    // L2: J=512 -> O=512
    gemm_sparse<512, false><<<Bc / 2, THREADS, 0, stream>>>(
        s1m, WT + WOFF2, 512, nullptr, s2m, nullptr, 0);
    // L3: J=512 -> O=256
    gemm_sparse<256, false><<<Bc / 4, THREADS, 0, stream>>>(
        s2m, WT + WOFF3, 512, nullptr, s3m, nullptr, 0);
    // L4 (readout): J=256 -> O=128 (padded), LI epilogue -> out
    gemm_sparse<128, true><<<Bc / 4, THREADS, 0, stream>>>(
        s3m, WT + WOFF4, 256, nullptr, nullptr, out, b0);
  }
}